// Round 7
// baseline (124.259 us; speedup 1.0000x reference)
//
#include <hip/hip_runtime.h>
#include <math.h>

typedef __attribute__((ext_vector_type(8))) short bf16x8;
typedef __attribute__((ext_vector_type(4))) float f32x4;

#define MFMA(a, b, c) __builtin_amdgcn_mfma_f32_16x16x32_bf16(a, b, c, 0, 0, 0)

constexpr int GN = 128;   // B*T
constexpr int NN = 512;   // nodes
constexpr int FD = 128;   // F_in == D == 128
#define LRELU(x) fmaxf((x), 0.2f * (x))
#define LOG2E 1.4426950408889634f

// round-to-nearest-even bf16 kept in the TOP 16 bits of a u32
__device__ inline unsigned rne_top16(float x) {
    unsigned u = __float_as_uint(x);
    return u + 0x7fffu + ((u >> 16) & 1u);
}
// pack top-16 of e0 (-> low half) and e1 (-> high half)
__device__ inline unsigned pack_top16(unsigned e1, unsigned e0) {
    return __builtin_amdgcn_perm(e1, e0, 0x07060302u);
}
// async global->LDS, 16 bytes per lane
__device__ inline void gload16(const void* g, void* l) {
    __builtin_amdgcn_global_load_lds(
        (const __attribute__((address_space(1))) unsigned*)g,
        (__attribute__((address_space(3))) unsigned*)l, 16, 0, 0);
}

// ---------------------------------------------------------------------------
// prep: blocks 0..31 adjacency bitmask (512 rows x 16 words);
//       blocks 32..63 W as bf16 hi(trunc)/lo(rne) in MFMA-B-fragment swizzle:
//       elem (k,d) -> ((kk*8+nb)*64 + lane)*8 + idx,
//       kk=k>>5, nb=d>>4, lane=(d&15)+16*((k>>3)&3), idx=k&7
// ---------------------------------------------------------------------------
__global__ __launch_bounds__(256) void prep_kernel(
    const int* __restrict__ adj, const float* __restrict__ W,
    unsigned* __restrict__ mask, unsigned short* __restrict__ wsHi,
    unsigned short* __restrict__ wsLo)
{
    const int b = blockIdx.x, t = threadIdx.x;
    if (b < 32) {
        const int wi = b * 256 + t;           // word index 0..8191
        const int row = wi >> 4, wo = wi & 15;
        const int* p = adj + row * NN + wo * 32;
        unsigned m = 0;
        #pragma unroll
        for (int q = 0; q < 32; q += 4) {
            int4 v = *(const int4*)&p[q];
            m |= (v.x > 0 ? 1u : 0u) << q;
            m |= (v.y > 0 ? 1u : 0u) << (q + 1);
            m |= (v.z > 0 ? 1u : 0u) << (q + 2);
            m |= (v.w > 0 ? 1u : 0u) << (q + 3);
        }
        mask[wi] = m;
    } else {
        const int base = (b - 32) * 512 + t * 2;
        #pragma unroll
        for (int q = 0; q < 2; ++q) {
            const int pos = base + q;
            const int idx = pos & 7, lane = (pos >> 3) & 63, cn = pos >> 9;
            const int kk = cn >> 3, nb = cn & 7;
            const int k = kk * 32 + ((lane >> 4) & 3) * 8 + idx;
            const int d = nb * 16 + (lane & 15);
            const float wv = W[k * FD + d];
            const unsigned u = __float_as_uint(wv);
            wsHi[pos] = (unsigned short)(u >> 16);                 // truncate
            wsLo[pos] = (unsigned short)(rne_top16(
                            wv - __uint_as_float(u & 0xffff0000u)) >> 16);
        }
    }
}

// ---------------------------------------------------------------------------
// whb: block (g, jt): Wh rows jt*128..+128 = h@W via 3-split bf16 MFMA.
// (unchanged from round 6 — known good)
// ---------------------------------------------------------------------------
__global__ __launch_bounds__(256, 2) void whb_kernel(
    const float* __restrict__ h, const float* __restrict__ a,
    const unsigned short* __restrict__ wsHi, const unsigned short* __restrict__ wsLo,
    unsigned short* __restrict__ whtHi, unsigned short* __restrict__ whtLo,
    float* __restrict__ esrc, float* __restrict__ edst)
{
    __shared__ __attribute__((aligned(16))) unsigned short sW[32768]; // 64 KB

    const int bid = blockIdx.x;
    const int xcd = bid & 7, slot = bid >> 3;
    const int g = xcd + 8 * (slot >> 2);
    const int jt = slot & 3;
    const int t = threadIdx.x, lane = t & 63, w = t >> 6;
    const int i0r = jt * 128;
    const int q8 = (lane >> 4) * 8;
    const float* hg = h + (size_t)(g * NN) * FD;

    float4 hv[16];
    #pragma unroll
    for (int kk = 0; kk < 4; ++kk)
        #pragma unroll
        for (int mt = 0; mt < 2; ++mt) {
            const float* src = hg + (size_t)(i0r + w * 32 + mt * 16 + (lane & 15)) * FD
                             + kk * 32 + q8;
            hv[(kk * 2 + mt) * 2 + 0] = *(const float4*)src;
            hv[(kk * 2 + mt) * 2 + 1] = *(const float4*)(src + 4);
        }
    for (int q = t; q < 2048; q += 256) {
        gload16(&wsHi[q * 8], &sW[q * 8]);
        gload16(&wsLo[q * 8], &sW[16384 + q * 8]);
    }
    __syncthreads();

    f32x4 acc[2][8];
    #pragma unroll
    for (int mt = 0; mt < 2; ++mt)
        #pragma unroll
        for (int nb = 0; nb < 8; ++nb) acc[mt][nb] = (f32x4){0.f, 0.f, 0.f, 0.f};

    #pragma unroll
    for (int kk = 0; kk < 4; ++kk) {
        bf16x8 ah[2], al[2];
        #pragma unroll
        for (int mt = 0; mt < 2; ++mt) {
            const float4 f0 = hv[(kk * 2 + mt) * 2 + 0];
            const float4 f1 = hv[(kk * 2 + mt) * 2 + 1];
            const float xs[8] = {f0.x, f0.y, f0.z, f0.w, f1.x, f1.y, f1.z, f1.w};
            union { bf16x8 v; unsigned u[4]; } H, L;
            #pragma unroll
            for (int j = 0; j < 4; ++j) {
                const unsigned e0 = __float_as_uint(xs[2 * j]);
                const unsigned e1 = __float_as_uint(xs[2 * j + 1]);
                H.u[j] = pack_top16(e1, e0);
                const unsigned l0 = rne_top16(xs[2*j]   - __uint_as_float(e0 & 0xffff0000u));
                const unsigned l1 = rne_top16(xs[2*j+1] - __uint_as_float(e1 & 0xffff0000u));
                L.u[j] = pack_top16(l1, l0);
            }
            ah[mt] = H.v; al[mt] = L.v;
        }
        #pragma unroll
        for (int nb = 0; nb < 8; ++nb) {
            const bf16x8 bh = *(const bf16x8*)&sW[((kk * 8 + nb) * 64 + lane) * 8];
            const bf16x8 bl = *(const bf16x8*)&sW[16384 + ((kk * 8 + nb) * 64 + lane) * 8];
            #pragma unroll
            for (int mt = 0; mt < 2; ++mt) {
                acc[mt][nb] = MFMA(al[mt], bh, acc[mt][nb]);
                acc[mt][nb] = MFMA(ah[mt], bl, acc[mt][nb]);
                acc[mt][nb] = MFMA(ah[mt], bh, acc[mt][nb]);
            }
        }
    }

    float av[8], bv[8];
    #pragma unroll
    for (int nb = 0; nb < 8; ++nb) {
        av[nb] = a[nb * 16 + (lane & 15)];
        bv[nb] = a[FD + nb * 16 + (lane & 15)];
    }
    #pragma unroll
    for (int mt = 0; mt < 2; ++mt)
        #pragma unroll
        for (int r = 0; r < 4; ++r) {
            float ps = 0.f, pd = 0.f;
            #pragma unroll
            for (int nb = 0; nb < 8; ++nb) {
                ps += acc[mt][nb][r] * av[nb];
                pd += acc[mt][nb][r] * bv[nb];
            }
            #pragma unroll
            for (int off = 1; off <= 8; off <<= 1) {
                ps += __shfl_xor(ps, off);
                pd += __shfl_xor(pd, off);
            }
            if ((lane & 15) == 0) {
                const int row = g * NN + i0r + w * 32 + mt * 16 + (lane >> 4) * 4 + r;
                esrc[row] = ps;
                edst[row] = pd;
            }
        }

    unsigned short* sTh = sW;            // 8192 shorts
    unsigned short* sTl = sW + 8192;     // 8192 shorts
    const size_t gbase = (size_t)g * 65536 + (size_t)jt * 16384;
    const int ib = 4 * ((lane >> 4) & 1);

    for (int ph = 0; ph < 2; ++ph) {
        __syncthreads();
        #pragma unroll
        for (int mt = 0; mt < 2; ++mt) {
            const int lp2 = (lane & 15) + 16 * (mt * 2 + (lane >> 5));
            #pragma unroll
            for (int nbp = 0; nbp < 4; ++nbp) {
                const int nb = ph * 4 + nbp;
                const int off = ((w * 4 + nbp) * 64 + lp2) * 8 + ib;
                const unsigned u0 = __float_as_uint(acc[mt][nb][0]);
                const unsigned u1 = __float_as_uint(acc[mt][nb][1]);
                const unsigned u2 = __float_as_uint(acc[mt][nb][2]);
                const unsigned u3 = __float_as_uint(acc[mt][nb][3]);
                *(uint2*)&sTh[off] = make_uint2(pack_top16(u1, u0), pack_top16(u3, u2));
                const unsigned l0 = rne_top16(acc[mt][nb][0] - __uint_as_float(u0 & 0xffff0000u));
                const unsigned l1 = rne_top16(acc[mt][nb][1] - __uint_as_float(u1 & 0xffff0000u));
                const unsigned l2 = rne_top16(acc[mt][nb][2] - __uint_as_float(u2 & 0xffff0000u));
                const unsigned l3 = rne_top16(acc[mt][nb][3] - __uint_as_float(u3 & 0xffff0000u));
                *(uint2*)&sTl[off] = make_uint2(pack_top16(l1, l0), pack_top16(l3, l2));
            }
        }
        __syncthreads();
        for (int q = t; q < 1024; q += 256) {
            const int qw = q >> 8, qr = q & 255;
            const size_t go = gbase + (size_t)(qw * 8 + ph * 4) * 512 + qr * 8;
            *(float4*)&whtHi[go] = *(const float4*)&sTh[q * 8];
            *(float4*)&whtLo[go] = *(const float4*)&sTl[q * 8];
        }
    }
}

// ---------------------------------------------------------------------------
// attn: block (g, it): 256 rows, grid 256 (1 block/CU), 64 rows PER WAVE
// (4x 16-row MFMA tiles) -> each wave amortizes the 256 KB of B-fragment
// LDS reads over 2x the rows of round 6 (per-CU LDS traffic halved).
// No max-subtraction (shift-invariant; masked -> p = 0 exactly). P truncated
// to bf16; lsum accumulates the truncated p (normalization cancels rounding).
// Double-buffered 32 KB chunks via global_load_lds; mask LDS stride 17
// (conflict-free). LDS ~83 KB. acc = 128 VGPRs, launch_bounds(256,1).
// ---------------------------------------------------------------------------
__global__ __launch_bounds__(256, 1) void attn_kernel(
    const unsigned short* __restrict__ whtHi, const unsigned short* __restrict__ whtLo,
    const float* __restrict__ esrc, const float* __restrict__ edst,
    const unsigned* __restrict__ mask, float* __restrict__ out)
{
    __shared__ __attribute__((aligned(16))) float eds[NN];              // 2 KB
    __shared__ unsigned maskS[256 * 17];                                // 17.4 KB
    __shared__ __attribute__((aligned(16))) unsigned short cHi[2][8192];// 32 KB
    __shared__ __attribute__((aligned(16))) unsigned short cLo[2][8192];// 32 KB

    const int bid = blockIdx.x;
    const int xcd = bid & 7, slot = bid >> 3;       // slot 0..31
    const int g = xcd + 8 * (slot >> 1);
    const int it = slot & 1;
    const int t = threadIdx.x, lane = t & 63, w = t >> 6;   // w 0..3
    const int i0 = it * 256;
    const int q8 = (lane >> 4) * 8;
    const int l15 = lane & 15;

    eds[t]       = edst[g * NN + t] * LOG2E;
    eds[t + 256] = edst[g * NN + 256 + t] * LOG2E;
    // mask rows i0..i0+255, LDS stride 17 (conflict-free column reads)
    {
        const unsigned* mr = &mask[(i0 + t) * 16];
        #pragma unroll
        for (int q = 0; q < 4; ++q) {
            const uint4 v = *(const uint4*)&mr[q * 4];
            maskS[t * 17 + q * 4 + 0] = v.x;
            maskS[t * 17 + q * 4 + 1] = v.y;
            maskS[t * 17 + q * 4 + 2] = v.z;
            maskS[t * 17 + q * 4 + 3] = v.w;
        }
    }
    float s[4];
    #pragma unroll
    for (int mt = 0; mt < 4; ++mt)
        s[mt] = esrc[g * NN + i0 + w * 64 + mt * 16 + l15] * LOG2E;

    // stage chunk 0 into buffer 0
    const size_t gbase = (size_t)g * 65536;
    for (int q = t; q < 1024; q += 256) {
        gload16(&whtHi[gbase + q * 8], &cHi[0][q * 8]);
        gload16(&whtLo[gbase + q * 8], &cLo[0][q * 8]);
    }
    __syncthreads();   // covers eds/maskS writes + chunk-0 staging

    f32x4 acc[4][8];
    #pragma unroll
    for (int mt = 0; mt < 4; ++mt)
        #pragma unroll
        for (int nb = 0; nb < 8; ++nb) acc[mt][nb] = (f32x4){0.f, 0.f, 0.f, 0.f};
    float lsum[4] = {0.f, 0.f, 0.f, 0.f};

    for (int c2 = 0; c2 < 8; ++c2) {
        const int cur = c2 & 1, nxt = cur ^ 1;
        if (c2 < 7) {                              // prefetch next chunk
            const size_t gb = gbase + (size_t)(c2 + 1) * 8192;
            for (int q = t; q < 1024; q += 256) {
                gload16(&whtHi[gb + q * 8], &cHi[nxt][q * 8]);
                gload16(&whtLo[gb + q * 8], &cLo[nxt][q * 8]);
            }
        }
        const unsigned short* __restrict__ bHi = &cHi[cur][0];
        const unsigned short* __restrict__ bLo = &cLo[cur][0];
        #pragma unroll
        for (int kl = 0; kl < 2; ++kl) {
            const int kk = c2 * 2 + kl;
            const float* ep = &eds[kk * 32 + q8];
            const float4 ed0 = *(const float4*)ep;
            const float4 ed1 = *(const float4*)(ep + 4);
            const float ev[8] = {ed0.x, ed0.y, ed0.z, ed0.w, ed1.x, ed1.y, ed1.z, ed1.w};

            union { bf16x8 v; unsigned u[4]; } H[4];
            #pragma unroll
            for (int mt = 0; mt < 4; ++mt) {
                const unsigned mw =
                    maskS[(w * 64 + mt * 16 + l15) * 17 + kk] >> q8;
                unsigned uh[8];
                #pragma unroll
                for (int i = 0; i < 8; ++i) {
                    const float z = s[mt] + ev[i];
                    float p = __builtin_amdgcn_exp2f(fmaxf(z, 0.2f * z));
                    p = ((mw >> i) & 1u) ? p : 0.f;
                    const unsigned u = __float_as_uint(p) & 0xffff0000u;
                    lsum[mt] += __uint_as_float(u);
                    uh[i] = u;
                }
                #pragma unroll
                for (int j = 0; j < 4; ++j)
                    H[mt].u[j] = pack_top16(uh[2*j+1], uh[2*j]);
            }
            #pragma unroll
            for (int nb = 0; nb < 8; ++nb) {
                const bf16x8 bl = *(const bf16x8*)&bLo[((kl * 8 + nb) * 64 + lane) * 8];
                const bf16x8 bh = *(const bf16x8*)&bHi[((kl * 8 + nb) * 64 + lane) * 8];
                #pragma unroll
                for (int mt = 0; mt < 4; ++mt) {
                    acc[mt][nb] = MFMA(H[mt].v, bl, acc[mt][nb]);
                    acc[mt][nb] = MFMA(H[mt].v, bh, acc[mt][nb]);
                }
            }
        }
        __syncthreads();   // all waves done with cur; prefetch into nxt landed
    }

    #pragma unroll
    for (int mt = 0; mt < 4; ++mt) {
        lsum[mt] += __shfl_xor(lsum[mt], 16);
        lsum[mt] += __shfl_xor(lsum[mt], 32);
    }

    #pragma unroll
    for (int mt = 0; mt < 4; ++mt)
        #pragma unroll
        for (int r = 0; r < 4; ++r) {
            const int rr = (lane >> 4) * 4 + r;        // row within 16-tile
            const float rl = 1.0f / __shfl(lsum[mt], rr);
            const int row = g * NN + i0 + w * 64 + mt * 16 + rr;
            #pragma unroll
            for (int nb = 0; nb < 8; ++nb)
                out[row * FD + nb * 16 + l15] = acc[mt][nb][r] * rl;
        }
}

// ---------------------------------------------------------------------------
extern "C" void kernel_launch(void* const* d_in, const int* in_sizes, int n_in,
                              void* d_out, int out_size, void* d_ws, size_t ws_size,
                              hipStream_t stream) {
    const float* h   = (const float*)d_in[0];
    const int*   adj = (const int*)d_in[1];
    const float* W   = (const float*)d_in[2];
    const float* a   = (const float*)d_in[3];
    float* out = (float*)d_out;

    unsigned short* whtHi = (unsigned short*)d_ws;                       // 16.78 MB
    unsigned short* whtLo = whtHi + (size_t)GN * 65536;                  // 16.78 MB
    float* esrc = (float*)(whtLo + (size_t)GN * 65536);                  // 256 KB
    float* edst = esrc + GN * NN;                                        // 256 KB
    unsigned* mask = (unsigned*)(edst + GN * NN);                        // 32 KB
    unsigned short* wsHi = (unsigned short*)(mask + 8192);               // 32 KB
    unsigned short* wsLo = wsHi + 16384;                                 // 32 KB

    prep_kernel<<<64, 256, 0, stream>>>(adj, W, mask, wsHi, wsLo);
    whb_kernel<<<512, 256, 0, stream>>>(h, a, wsHi, wsLo, whtHi, whtLo, esrc, edst);
    attn_kernel<<<256, 256, 0, stream>>>(whtHi, whtLo, esrc, edst, mask, out);
}

// Round 8
// 116.502 us; speedup vs baseline: 1.0666x; 1.0666x over previous
//
#include <hip/hip_runtime.h>
#include <math.h>

typedef __attribute__((ext_vector_type(8))) short bf16x8;
typedef __attribute__((ext_vector_type(4))) float f32x4;

#define MFMA(a, b, c) __builtin_amdgcn_mfma_f32_16x16x32_bf16(a, b, c, 0, 0, 0)

constexpr int GN = 128;   // B*T
constexpr int NN = 512;   // nodes
constexpr int FD = 128;   // F_in == D == 128
#define LOG2E 1.4426950408889634f

// round-to-nearest-even bf16 kept in the TOP 16 bits of a u32
__device__ inline unsigned rne_top16(float x) {
    unsigned u = __float_as_uint(x);
    return u + 0x7fffu + ((u >> 16) & 1u);
}
// pack top-16 of e0 (-> low half) and e1 (-> high half)
__device__ inline unsigned pack_top16(unsigned e1, unsigned e0) {
    return __builtin_amdgcn_perm(e1, e0, 0x07060302u);
}
// async global->LDS, 16 bytes per lane
__device__ inline void gload16(const void* g, void* l) {
    __builtin_amdgcn_global_load_lds(
        (const __attribute__((address_space(1))) unsigned*)g,
        (__attribute__((address_space(3))) unsigned*)l, 16, 0, 0);
}

// ---------------------------------------------------------------------------
// prep: blocks 0..31 adjacency bitmask (512 rows x 16 words);
//       blocks 32..63 W as bf16 hi(trunc)/lo(rne) in MFMA-B-fragment swizzle:
//       elem (k,d) -> ((kk*8+nb)*64 + lane)*8 + idx,
//       kk=k>>5, nb=d>>4, lane=(d&15)+16*((k>>3)&3), idx=k&7
// ---------------------------------------------------------------------------
__global__ __launch_bounds__(256) void prep_kernel(
    const int* __restrict__ adj, const float* __restrict__ W,
    unsigned* __restrict__ mask, unsigned short* __restrict__ wsHi,
    unsigned short* __restrict__ wsLo)
{
    const int b = blockIdx.x, t = threadIdx.x;
    if (b < 32) {
        const int wi = b * 256 + t;           // word index 0..8191
        const int row = wi >> 4, wo = wi & 15;
        const int* p = adj + row * NN + wo * 32;
        unsigned m = 0;
        #pragma unroll
        for (int q = 0; q < 32; q += 4) {
            int4 v = *(const int4*)&p[q];
            m |= (v.x > 0 ? 1u : 0u) << q;
            m |= (v.y > 0 ? 1u : 0u) << (q + 1);
            m |= (v.z > 0 ? 1u : 0u) << (q + 2);
            m |= (v.w > 0 ? 1u : 0u) << (q + 3);
        }
        mask[wi] = m;
    } else {
        const int base = (b - 32) * 512 + t * 2;
        #pragma unroll
        for (int q = 0; q < 2; ++q) {
            const int pos = base + q;
            const int idx = pos & 7, lane = (pos >> 3) & 63, cn = pos >> 9;
            const int kk = cn >> 3, nb = cn & 7;
            const int k = kk * 32 + ((lane >> 4) & 3) * 8 + idx;
            const int d = nb * 16 + (lane & 15);
            const float wv = W[k * FD + d];
            const unsigned u = __float_as_uint(wv);
            wsHi[pos] = (unsigned short)(u >> 16);                 // truncate
            wsLo[pos] = (unsigned short)(rne_top16(
                            wv - __uint_as_float(u & 0xffff0000u)) >> 16);
        }
    }
}

// ---------------------------------------------------------------------------
// whb: block (g, jt): Wh rows jt*128..+128 = h@W via 3-split bf16 MFMA.
// W hi+lo (64 KB) staged once via global_load_lds; h loads into registers
// before the barrier; K-loop barrier-free. Outputs: esrc/edst fp32; WhT as
// SINGLE RNE bf16 in global B-fragment swizzle (elem (j,d) of g at
// g*65536 + ((KK*8+nb)*64 + lanep)*8 + idx, KK=j>>5, nb=d>>4,
// lanep=(d&15)+16*((j>>3)&3), idx=j&7). Single-pass transpose via LDS.
// ---------------------------------------------------------------------------
__global__ __launch_bounds__(256, 2) void whb_kernel(
    const float* __restrict__ h, const float* __restrict__ a,
    const unsigned short* __restrict__ wsHi, const unsigned short* __restrict__ wsLo,
    unsigned short* __restrict__ whtHi,
    float* __restrict__ esrc, float* __restrict__ edst)
{
    __shared__ __attribute__((aligned(16))) unsigned short sW[32768]; // 64 KB

    const int bid = blockIdx.x;
    const int xcd = bid & 7, slot = bid >> 3;
    const int g = xcd + 8 * (slot >> 2);
    const int jt = slot & 3;
    const int t = threadIdx.x, lane = t & 63, w = t >> 6;
    const int i0r = jt * 128;
    const int q8 = (lane >> 4) * 8;
    const float* hg = h + (size_t)(g * NN) * FD;

    // issue all h loads first (registers), then W staging, then barrier
    float4 hv[16];
    #pragma unroll
    for (int kk = 0; kk < 4; ++kk)
        #pragma unroll
        for (int mt = 0; mt < 2; ++mt) {
            const float* src = hg + (size_t)(i0r + w * 32 + mt * 16 + (lane & 15)) * FD
                             + kk * 32 + q8;
            hv[(kk * 2 + mt) * 2 + 0] = *(const float4*)src;
            hv[(kk * 2 + mt) * 2 + 1] = *(const float4*)(src + 4);
        }
    for (int q = t; q < 2048; q += 256) {
        gload16(&wsHi[q * 8], &sW[q * 8]);
        gload16(&wsLo[q * 8], &sW[16384 + q * 8]);
    }
    __syncthreads();

    f32x4 acc[2][8];
    #pragma unroll
    for (int mt = 0; mt < 2; ++mt)
        #pragma unroll
        for (int nb = 0; nb < 8; ++nb) acc[mt][nb] = (f32x4){0.f, 0.f, 0.f, 0.f};

    #pragma unroll
    for (int kk = 0; kk < 4; ++kk) {
        bf16x8 ah[2], al[2];
        #pragma unroll
        for (int mt = 0; mt < 2; ++mt) {
            const float4 f0 = hv[(kk * 2 + mt) * 2 + 0];
            const float4 f1 = hv[(kk * 2 + mt) * 2 + 1];
            const float xs[8] = {f0.x, f0.y, f0.z, f0.w, f1.x, f1.y, f1.z, f1.w};
            union { bf16x8 v; unsigned u[4]; } H, L;
            #pragma unroll
            for (int j = 0; j < 4; ++j) {
                const unsigned e0 = __float_as_uint(xs[2 * j]);
                const unsigned e1 = __float_as_uint(xs[2 * j + 1]);
                H.u[j] = pack_top16(e1, e0);
                const unsigned l0 = rne_top16(xs[2*j]   - __uint_as_float(e0 & 0xffff0000u));
                const unsigned l1 = rne_top16(xs[2*j+1] - __uint_as_float(e1 & 0xffff0000u));
                L.u[j] = pack_top16(l1, l0);
            }
            ah[mt] = H.v; al[mt] = L.v;
        }
        #pragma unroll
        for (int nb = 0; nb < 8; ++nb) {
            const bf16x8 bh = *(const bf16x8*)&sW[((kk * 8 + nb) * 64 + lane) * 8];
            const bf16x8 bl = *(const bf16x8*)&sW[16384 + ((kk * 8 + nb) * 64 + lane) * 8];
            #pragma unroll
            for (int mt = 0; mt < 2; ++mt) {
                acc[mt][nb] = MFMA(al[mt], bh, acc[mt][nb]);
                acc[mt][nb] = MFMA(ah[mt], bl, acc[mt][nb]);
                acc[mt][nb] = MFMA(ah[mt], bh, acc[mt][nb]);
            }
        }
    }

    // ---- esrc / edst: per-row dot with a_src / a_dst, reduce over 16 lanes ----
    float av[8], bv[8];
    #pragma unroll
    for (int nb = 0; nb < 8; ++nb) {
        av[nb] = a[nb * 16 + (lane & 15)];
        bv[nb] = a[FD + nb * 16 + (lane & 15)];
    }
    #pragma unroll
    for (int mt = 0; mt < 2; ++mt)
        #pragma unroll
        for (int r = 0; r < 4; ++r) {
            float ps = 0.f, pd = 0.f;
            #pragma unroll
            for (int nb = 0; nb < 8; ++nb) {
                ps += acc[mt][nb][r] * av[nb];
                pd += acc[mt][nb][r] * bv[nb];
            }
            #pragma unroll
            for (int off = 1; off <= 8; off <<= 1) {
                ps += __shfl_xor(ps, off);
                pd += __shfl_xor(pd, off);
            }
            if ((lane & 15) == 0) {
                const int row = g * NN + i0r + w * 32 + mt * 16 + (lane >> 4) * 4 + r;
                esrc[row] = ps;
                edst[row] = pd;
            }
        }

    // ---- transpose Wh -> swizzled single RNE bf16, ONE pass (reuse sW) ----
    unsigned short* sT = sW;             // 16384 shorts (32 KB)
    const size_t gbase = (size_t)g * 65536 + (size_t)jt * 16384;
    const int ib = 4 * ((lane >> 4) & 1);

    __syncthreads();                     // everyone done reading sW
    #pragma unroll
    for (int mt = 0; mt < 2; ++mt) {
        const int lp2 = (lane & 15) + 16 * (mt * 2 + (lane >> 5));
        #pragma unroll
        for (int nb = 0; nb < 8; ++nb) {
            const int off = ((w * 8 + nb) * 64 + lp2) * 8 + ib;
            const unsigned r0 = rne_top16(acc[mt][nb][0]);
            const unsigned r1 = rne_top16(acc[mt][nb][1]);
            const unsigned r2 = rne_top16(acc[mt][nb][2]);
            const unsigned r3 = rne_top16(acc[mt][nb][3]);
            *(uint2*)&sT[off] = make_uint2(pack_top16(r1, r0), pack_top16(r3, r2));
        }
    }
    __syncthreads();
    for (int q = t; q < 2048; q += 256)
        *(float4*)&whtHi[gbase + q * 8] = *(const float4*)&sT[q * 8];
}

// ---------------------------------------------------------------------------
// attn: block (g, it): 128 rows (2 row-tiles/wave), grid 512 (2 blocks/CU —
// r7 showed 1 block/CU exposes the chunk barrier; keep 2). B operand is
// SINGLE bf16 Wh (error analysis: ~7e-5 contribution after p/l-weighted
// averaging; P-truncation at 2^-8 dominates and lsum cancels its common
// mode). No max-subtraction (shift-invariant; masked -> p = 0 exactly).
// Double-buffered 16 KB chunks via global_load_lds; mask LDS stride 17.
// LDS = 32 + 2 + 8.5 ~ 42.5 KB.
// ---------------------------------------------------------------------------
__global__ __launch_bounds__(256, 2) void attn_kernel(
    const unsigned short* __restrict__ whtHi,
    const float* __restrict__ esrc, const float* __restrict__ edst,
    const unsigned* __restrict__ mask, float* __restrict__ out)
{
    __shared__ __attribute__((aligned(16))) float eds[NN];              // 2 KB
    __shared__ unsigned maskS[128 * 17];                                // 8.5 KB
    __shared__ __attribute__((aligned(16))) unsigned short cHi[2][8192];// 32 KB

    const int bid = blockIdx.x;
    const int xcd = bid & 7, slot = bid >> 3;
    const int g = xcd + 8 * (slot >> 2);
    const int it = slot & 3;
    const int t = threadIdx.x, lane = t & 63, w = t >> 6;
    const int i0 = it * 128;
    const int q8 = (lane >> 4) * 8;
    const int l15 = lane & 15;

    eds[t]       = edst[g * NN + t] * LOG2E;
    eds[t + 256] = edst[g * NN + 256 + t] * LOG2E;
    for (int q = t; q < 2048; q += 256) {        // 128 rows x 16 words
        const int row = q >> 4, wo = q & 15;
        maskS[row * 17 + wo] = mask[(i0 + row) * 16 + wo];
    }

    const int rloc0 = w * 32 + l15;              // local row in [0,128)
    const int rloc1 = rloc0 + 16;
    const float s0 = esrc[g * NN + i0 + rloc0] * LOG2E;
    const float s1 = esrc[g * NN + i0 + rloc1] * LOG2E;

    // stage chunk 0 into buffer 0 (chunk = 64 j-rows = 8192 shorts)
    const size_t gbase = (size_t)g * 65536;
    for (int q = t; q < 1024; q += 256)
        gload16(&whtHi[gbase + q * 8], &cHi[0][q * 8]);
    __syncthreads();   // covers eds/maskS writes + chunk-0 staging

    f32x4 acc[2][8];
    #pragma unroll
    for (int mt = 0; mt < 2; ++mt)
        #pragma unroll
        for (int nb = 0; nb < 8; ++nb) acc[mt][nb] = (f32x4){0.f, 0.f, 0.f, 0.f};
    float lsum0 = 0.f, lsum1 = 0.f;

    for (int c2 = 0; c2 < 8; ++c2) {
        const int cur = c2 & 1, nxt = cur ^ 1;
        if (c2 < 7) {                              // prefetch next chunk
            const size_t gb = gbase + (size_t)(c2 + 1) * 8192;
            for (int q = t; q < 1024; q += 256)
                gload16(&whtHi[gb + q * 8], &cHi[nxt][q * 8]);
        }
        const unsigned short* __restrict__ bHi = &cHi[cur][0];
        #pragma unroll
        for (int kl = 0; kl < 2; ++kl) {
            const int kk = c2 * 2 + kl;
            const float* ep = &eds[kk * 32 + q8];
            const float4 ed0 = *(const float4*)ep;
            const float4 ed1 = *(const float4*)(ep + 4);
            const float ev[8] = {ed0.x, ed0.y, ed0.z, ed0.w, ed1.x, ed1.y, ed1.z, ed1.w};
            const unsigned mw0 = maskS[rloc0 * 17 + kk] >> q8;
            const unsigned mw1 = maskS[rloc1 * 17 + kk] >> q8;

            union { bf16x8 v; unsigned u[4]; } H0, H1;
            unsigned uh0[8], uh1[8];
            #pragma unroll
            for (int i = 0; i < 8; ++i) {
                const float z0 = s0 + ev[i];
                float p0 = __builtin_amdgcn_exp2f(fmaxf(z0, 0.2f * z0));
                p0 = ((mw0 >> i) & 1u) ? p0 : 0.f;
                const unsigned u0 = __float_as_uint(p0) & 0xffff0000u;
                lsum0 += __uint_as_float(u0);
                uh0[i] = u0;
                const float z1 = s1 + ev[i];
                float p1 = __builtin_amdgcn_exp2f(fmaxf(z1, 0.2f * z1));
                p1 = ((mw1 >> i) & 1u) ? p1 : 0.f;
                const unsigned u1 = __float_as_uint(p1) & 0xffff0000u;
                lsum1 += __uint_as_float(u1);
                uh1[i] = u1;
            }
            #pragma unroll
            for (int j = 0; j < 4; ++j) {
                H0.u[j] = pack_top16(uh0[2*j+1], uh0[2*j]);
                H1.u[j] = pack_top16(uh1[2*j+1], uh1[2*j]);
            }
            #pragma unroll
            for (int nb = 0; nb < 8; ++nb) {
                const bf16x8 bh = *(const bf16x8*)&bHi[((kl * 8 + nb) * 64 + lane) * 8];
                acc[0][nb] = MFMA(H0.v, bh, acc[0][nb]);
                acc[1][nb] = MFMA(H1.v, bh, acc[1][nb]);
            }
        }
        __syncthreads();   // all waves done with cur; prefetch into nxt landed
    }

    lsum0 += __shfl_xor(lsum0, 16); lsum0 += __shfl_xor(lsum0, 32);
    lsum1 += __shfl_xor(lsum1, 16); lsum1 += __shfl_xor(lsum1, 32);

    #pragma unroll
    for (int r = 0; r < 4; ++r) {
        const int rr = (lane >> 4) * 4 + r;            // row within 16-tile
        const float rl0 = 1.0f / __shfl(lsum0, rr);
        const float rl1 = 1.0f / __shfl(lsum1, rr);
        const int row0 = g * NN + i0 + w * 32 + rr;
        const int row1 = row0 + 16;
        #pragma unroll
        for (int nb = 0; nb < 8; ++nb) {
            out[row0 * FD + nb * 16 + l15] = acc[0][nb][r] * rl0;
            out[row1 * FD + nb * 16 + l15] = acc[1][nb][r] * rl1;
        }
    }
}

// ---------------------------------------------------------------------------
extern "C" void kernel_launch(void* const* d_in, const int* in_sizes, int n_in,
                              void* d_out, int out_size, void* d_ws, size_t ws_size,
                              hipStream_t stream) {
    const float* h   = (const float*)d_in[0];
    const int*   adj = (const int*)d_in[1];
    const float* W   = (const float*)d_in[2];
    const float* a   = (const float*)d_in[3];
    float* out = (float*)d_out;

    unsigned short* whtHi = (unsigned short*)d_ws;                       // 16.78 MB
    float* esrc = (float*)(whtHi + (size_t)GN * 65536);                  // 256 KB
    float* edst = esrc + GN * NN;                                        // 256 KB
    unsigned* mask = (unsigned*)(edst + GN * NN);                        // 32 KB
    unsigned short* wsHi = (unsigned short*)(mask + 8192);               // 32 KB
    unsigned short* wsLo = wsHi + 16384;                                 // 32 KB

    prep_kernel<<<64, 256, 0, stream>>>(adj, W, mask, wsHi, wsLo);
    whb_kernel<<<512, 256, 0, stream>>>(h, a, wsHi, wsLo, whtHi, esrc, edst);
    attn_kernel<<<512, 256, 0, stream>>>(whtHi, esrc, edst, mask, out);
}